// Round 4
// baseline (184.330 us; speedup 1.0000x reference)
//
#include <hip/hip_runtime.h>
#include <hip/hip_cooperative_groups.h>

namespace cg = cooperative_groups;

// Problem constants (match reference setup_inputs)
constexpr int T_DIM = 512;
constexpr int B_DIM = 32;
constexpr int L_DIM = 64;   // == wave size
constexpr int V_DIM = 10000;
constexpr int TC    = 32;                    // t-chunks per batch
constexpr int T_PER_BLOCK = T_DIM / TC;      // 16 t's per block
constexpr int T_PER_WAVE  = T_PER_BLOCK / 4; // 4 t's per wave (256-thread block)
constexpr int NBLK = B_DIM * TC;             // 1024 blocks, all co-resident (4/CU)

// Single cooperative kernel:
//  Phase 1 (all 1024 blocks): per-(b,tc) partial column sums for the 64 label
//    entries + blank column. Row-major gather — each wave's 64 lanes read
//    within ONE contiguous 40KB row x[t,b,:]. DRAM-line-bound (~125 MB).
//  grid.sync()
//  Phase 2 (blocks 0..31): block b sums its TC partials (coalesced 8KB),
//    applies -w*log(avg+1e-10), atomicAdd into out (zeroed pre-sync).
__global__ __launch_bounds__(256) void ACE_fused_k(const float* __restrict__ x,
                                                   const int* __restrict__ label,
                                                   float* __restrict__ part_label,
                                                   float* __restrict__ part_blank,
                                                   float* __restrict__ out) {
    const int bid  = blockIdx.x;
    const int b    = bid & (B_DIM - 1);  // 0..31
    const int tc   = bid >> 5;           // 0..31
    const int tid  = threadIdx.x;        // 0..255
    const int w    = tid >> 6;           // wave 0..3
    const int lane = tid & 63;

    __shared__ float lds[256];
    __shared__ float ldsb[T_PER_BLOCK];

    // ---- Phase 1: gather ----
    if (tid < T_PER_BLOCK) {
        size_t t = (size_t)tc * T_PER_BLOCK + tid;
        ldsb[tid] = x[(t * B_DIM + b) * V_DIM];   // blank column x[t,b,0]
    }

    const int lab = label[b * L_DIM + lane];

    float s = 0.0f;
    if (lab != 0) {
        const int t0 = tc * T_PER_BLOCK + w * T_PER_WAVE;
        const float* p = x + ((size_t)t0 * B_DIM + b) * V_DIM + lab;
#pragma unroll
        for (int k = 0; k < T_PER_WAVE; ++k)
            s += p[(size_t)k * B_DIM * V_DIM];
    }
    lds[tid] = s;
    __syncthreads();

    if (tid < 64) {
        part_label[((size_t)b * TC + tc) * 64 + tid] =
            lds[tid] + lds[tid + 64] + lds[tid + 128] + lds[tid + 192];
    }
    if (tid == 0) {
        float bs = 0.0f;
#pragma unroll
        for (int k = 0; k < T_PER_BLOCK; ++k) bs += ldsb[k];
        part_blank[b * TC + tc] = bs;
        if (bid == 0) atomicExch(out, 0.0f);  // zero out at the coherent atomic point
    }

    __threadfence();        // partials visible device-wide before the barrier
    cg::this_grid().sync(); // acq-rel grid barrier

    // ---- Phase 2: finalize, blocks 0..31 (one per batch) ----
    if (bid >= B_DIM) return;
    const int bb = bid;

    // wave w sums tc-range [w*8, w*8+8) for entry = lane; cross-wave via LDS.
    float tot = 0.0f;
#pragma unroll
    for (int k = 0; k < TC / 4; ++k) {
        int tcc = w * (TC / 4) + k;
        tot += part_label[((size_t)bb * TC + tcc) * 64 + lane];
    }
    lds[tid] = tot;
    __syncthreads();

    if (tid < 64) {  // wave 0 only — ballot/shfl are wave-uniform here
        const int lab2 = label[bb * L_DIM + lane];
        float tt = lds[lane] + lds[lane + 64] + lds[lane + 128] + lds[lane + 192];
        float local = 0.0f;
        if (lab2 != 0) local = -logf(tt * (1.0f / T_DIM) + 1e-10f);

        unsigned long long nz = __ballot(lab2 != 0);
        if (lane == 0) {
            int len = __popcll(nz);
            float bs = 0.0f;
#pragma unroll
            for (int k = 0; k < TC; ++k) bs += part_blank[bb * TC + k];
            local += -(float)(T_DIM - len) * logf(bs * (1.0f / T_DIM) + 1e-10f);
        }
#pragma unroll
        for (int off = 32; off; off >>= 1) local += __shfl_down(local, off);

        if (lane == 0)
            atomicAdd(out, local * (1.0f / ((float)T_DIM * (float)B_DIM)));
    }
}

extern "C" void kernel_launch(void* const* d_in, const int* in_sizes, int n_in,
                              void* d_out, int out_size, void* d_ws, size_t ws_size,
                              hipStream_t stream) {
    const float* x     = (const float*)d_in[0];  // [T, B, V] float32
    const int*   label = (const int*)d_in[1];    // [B, L] int32
    float* out = (float*)d_out;

    float* part_label = (float*)d_ws;                          // 32*32*64 floats = 256 KB
    float* part_blank = part_label + (size_t)B_DIM * TC * 64;  // 1024 floats

    void* args[] = {(void*)&x, (void*)&label, (void*)&part_label,
                    (void*)&part_blank, (void*)&out};
    hipLaunchCooperativeKernel((const void*)ACE_fused_k, dim3(NBLK), dim3(256),
                               args, 0, stream);
}

// Round 5
// 29.421 us; speedup vs baseline: 6.2653x; 6.2653x over previous
//
#include <hip/hip_runtime.h>

// Problem constants (match reference setup_inputs)
constexpr int T_DIM = 512;
constexpr int B_DIM = 32;
constexpr int L_DIM = 64;   // == wave size
constexpr int V_DIM = 10000;
constexpr int TC    = 32;            // t-chunks per batch
constexpr int T_PER_BLOCK = T_DIM / TC;      // 16 t's per block
constexpr int T_PER_WAVE  = T_PER_BLOCK / 4; // 4 t's per wave (256-thread block)

// Kernel 1: per-(b, t-chunk) partial column sums for the 64 label entries
// plus the blank (v=0) column. Row-major gather: each wave's 64 lanes read
// within ONE contiguous 40KB row x[t,b,:]. DRAM-line-bound: ~1M distinct
// 128B lines ~= 124 MB -> ~20us floor at 6.3 TB/s; ~23us with random-line
// derate. This is the structural floor — positions are data-dependent.
__global__ __launch_bounds__(256) void ACE_gather_k(const float* __restrict__ x,
                                                    const int* __restrict__ label,
                                                    float* __restrict__ part_label,
                                                    float* __restrict__ part_blank) {
    const int b    = blockIdx.x;   // 0..31
    const int tc   = blockIdx.y;   // 0..31
    const int tid  = threadIdx.x;  // 0..255
    const int w    = tid >> 6;     // wave 0..3
    const int lane = tid & 63;

    __shared__ float lds[256];
    __shared__ float ldsb[T_PER_BLOCK];

    // Blank column partial: threads 0..15 each load one x[t,b,0].
    if (tid < T_PER_BLOCK) {
        size_t t = (size_t)tc * T_PER_BLOCK + tid;
        ldsb[tid] = x[(t * B_DIM + b) * V_DIM];
    }

    const int lab = label[b * L_DIM + lane];

    float s = 0.0f;
    if (lab != 0) {
        const int t0 = tc * T_PER_BLOCK + w * T_PER_WAVE;
        const float* p = x + ((size_t)t0 * B_DIM + b) * V_DIM + lab;
#pragma unroll
        for (int k = 0; k < T_PER_WAVE; ++k) {
            s += p[(size_t)k * B_DIM * V_DIM];
        }
    }
    lds[tid] = s;
    __syncthreads();

    if (tid < 64) {
        float tot = lds[tid] + lds[tid + 64] + lds[tid + 128] + lds[tid + 192];
        part_label[((size_t)b * TC + tc) * 64 + tid] = tot;
    }
    if (tid == 0) {
        float bs = 0.0f;
#pragma unroll
        for (int k = 0; k < T_PER_BLOCK; ++k) bs += ldsb[k];
        part_blank[b * TC + tc] = bs;
    }
}

// Kernel 2: widened finalize — 1024 threads / 16 waves, each wave owns 2
// batches. Coalesced 256B loads, TC-deep unroll for latency hiding.
// Deterministic scalar write; no atomics.
__global__ __launch_bounds__(1024) void ACE_finalize_k(const float* __restrict__ part_label,
                                                       const float* __restrict__ part_blank,
                                                       const int* __restrict__ label,
                                                       float* __restrict__ out) {
    const int tid  = threadIdx.x;
    const int w    = tid >> 6;     // 0..15
    const int lane = tid & 63;

    float local = 0.0f;
#pragma unroll
    for (int j = 0; j < 2; ++j) {
        const int b = w * 2 + j;
        const int lab = label[b * L_DIM + lane];

        // Unconditional coalesced partial-sum load (keeps loads uniform).
        float tot = 0.0f;
#pragma unroll
        for (int tc = 0; tc < TC; ++tc)
            tot += part_label[((size_t)b * TC + tc) * 64 + lane];
        if (lab != 0)
            local += -logf(tot * (1.0f / T_DIM) + 1e-10f);

        unsigned long long nz = __ballot(lab != 0);
        if (lane == 0) {
            int len = __popcll(nz);
            float bs = 0.0f;
#pragma unroll
            for (int tc = 0; tc < TC; ++tc) bs += part_blank[b * TC + tc];
            local += -(float)(T_DIM - len) * logf(bs * (1.0f / T_DIM) + 1e-10f);
        }
    }

    // Wave-64 reduction, then cross-wave via LDS.
#pragma unroll
    for (int off = 32; off; off >>= 1) local += __shfl_down(local, off);

    __shared__ float r[16];
    if (lane == 0) r[w] = local;
    __syncthreads();
    if (tid == 0) {
        float s = 0.0f;
#pragma unroll
        for (int k = 0; k < 16; ++k) s += r[k];
        out[0] = s * (1.0f / ((float)T_DIM * (float)B_DIM));
    }
}

extern "C" void kernel_launch(void* const* d_in, const int* in_sizes, int n_in,
                              void* d_out, int out_size, void* d_ws, size_t ws_size,
                              hipStream_t stream) {
    const float* x     = (const float*)d_in[0];  // [T, B, V] float32
    const int*   label = (const int*)d_in[1];    // [B, L] int32
    float* out = (float*)d_out;

    float* part_label = (float*)d_ws;                          // 32*32*64 floats = 256 KB
    float* part_blank = part_label + (size_t)B_DIM * TC * 64;  // 1024 floats

    dim3 grid(B_DIM, TC);
    ACE_gather_k<<<grid, 256, 0, stream>>>(x, label, part_label, part_blank);
    ACE_finalize_k<<<1, 1024, 0, stream>>>(part_label, part_blank, label, out);
}